// Round 6
// baseline (86.972 us; speedup 1.0000x reference)
//
#include <hip/hip_runtime.h>

// out[b] = P @ X[b] @ P^T, P (7140x1024) 0/1 with one 1 per column => scatter:
// out[b][rank(i)][rank(j)] = X[b][i][j], zeros elsewhere.
// FUSED, one block per output row: every block writes its zero row
// (memset-shaped); the 2048 data rows (found by unranking the row index —
// no LUT/LDS) then overwrite their 256 data chunks via one unaligned
// f32x4 store per lane into lines still dirty in this XCD's L2.

constexpr int D_IN  = 1024;
constexpr int D_OUT = 7140;            // C(36,3)
constexpr int VROW  = D_OUT / 4;       // 1785 float4 per output row
constexpr int NROWS = 2 * D_OUT;       // 14280

typedef float f32x4 __attribute__((ext_vector_type(4)));
typedef f32x4 f32x4u __attribute__((aligned(4)));   // unaligned 16B store

// rank of (a,b,c), 0<=a<b<c<36, among C(36,3) combos (closed form, verified R5)
__device__ __forceinline__ int rank36_3(int a, int b, int c) {
    int s1 = 7140 - (36 - a) * (35 - a) * (34 - a) / 6;
    int s2 = ((34 - a) * (35 - a) - (35 - b) * (36 - b)) / 2;
    return s1 + s2 + (c - b - 1);
}

__global__ __launch_bounds__(256) void sandwich_fused_kernel(
    const float* __restrict__ in, float* __restrict__ out)
{
    const int row = blockIdx.x;            // bb*D_OUT + o
    const int bb  = row >= D_OUT;
    const int o   = row - bb * D_OUT;

    // unrank o -> combination (a < b < c); blockIdx-uniform => scalar path
    int r = o, a = 0;
    for (;;) { int cnt = (35 - a) * (34 - a) / 2; if (r < cnt) break; r -= cnt; ++a; }
    int b = a + 1;
    for (;;) { int cnt = 35 - b; if (r < cnt) break; r -= cnt; ++b; }
    const int c = b + 1 + r;

    // zero the row (memset-shaped: 6 full rounds + 249-lane tail)
    f32x4* __restrict__ orow = reinterpret_cast<f32x4*>(out) + (size_t)row * VROW;
    const f32x4 z = (f32x4)(0.f);
    {
        int p = threadIdx.x;
        #pragma unroll
        for (int k = 0; k < 6; ++k, p += 256) orow[p] = z;
        if (p < VROW) orow[p] = z;
    }

    // data row iff (a,b,c) = (line, 16+col, 32+ch)
    if (a < 16 && b >= 16 && b < 32 && c >= 32) {
        const int t = ((a * 16 + (b - 16)) << 2) + (c - 32);   // source row index

        // lane k owns source chunk (line=k>>4, col=k&15), columns 4k..4k+3,
        // landing at 4 consecutive output columns starting at rank(line,16+col,32)
        const int k    = threadIdx.x;
        const int line = k >> 4;
        const int col  = k & 15;
        const f32x4 v  = *reinterpret_cast<const f32x4*>(
            in + (size_t)bb * (D_IN * D_IN) + (size_t)t * D_IN + (k << 2));
        const int c0   = rank36_3(line, 16 + col, 32);

        __syncthreads();   // drain this block's zero-stores before overwrite
        float* __restrict__ of = out + (size_t)row * D_OUT;
        *reinterpret_cast<f32x4u*>(of + c0) = v;
    }
}

extern "C" void kernel_launch(void* const* d_in, const int* in_sizes, int n_in,
                              void* d_out, int out_size, void* d_ws, size_t ws_size,
                              hipStream_t stream) {
    const float* in = (const float*)d_in[0];   // (2, 1024, 1024) f32
    float* out = (float*)d_out;                // (2, 7140, 7140) f32

    hipLaunchKernelGGL(sandwich_fused_kernel, dim3(NROWS), dim3(256), 0, stream,
                       in, out);
}

// Round 7
// 78.035 us; speedup vs baseline: 1.1145x; 1.1145x over previous
//
#include <hip/hip_runtime.h>

// out[b] = P @ X[b] @ P^T, P (7140x1024) 0/1 with one 1 per column => scatter:
// out[b][rank(i)][rank(j)] = X[b][i][j], zeros elsewhere.
// Zero-fill via hipMemsetAsync (dispatches rocclr fillBufferAligned, measured
// 6.9-7.1 TB/s — 1.4x our best HIP store loop), then a tiny scatter kernel
// writes the 2M data elements (one unaligned f32x4 store per lane).

constexpr int D_IN  = 1024;
constexpr int D_OUT = 7140;            // C(36,3)

typedef float f32x4 __attribute__((ext_vector_type(4)));
typedef f32x4 f32x4u __attribute__((aligned(4)));   // unaligned 16B store

// rank of (a,b,c), 0<=a<b<c<36, among C(36,3) combos (closed form, verified R5)
__device__ __forceinline__ int rank36_3(int a, int b, int c) {
    int s1 = 7140 - (36 - a) * (35 - a) * (34 - a) / 6;
    int s2 = ((34 - a) * (35 - a) - (35 - b) * (36 - b)) / 2;
    return s1 + s2 + (c - b - 1);
}

// one block per source row; coalesced f32x4 read, rank-scatter f32x4 store
__global__ __launch_bounds__(256) void scatter_rows_kernel(
    const float* __restrict__ in, float* __restrict__ out)
{
    const int bb = blockIdx.x >> 10;          // batch
    const int t  = blockIdx.x & 1023;         // source row index

    // output row = rank of source row's combination (block-uniform)
    const int o = rank36_3(t >> 6, 16 + ((t >> 2) & 15), 32 + (t & 3));

    // lane k owns source columns 4k..4k+3 (line=k>>4, col=k&15, ch=0..3)
    // => 4 consecutive output columns starting at rank(line,16+col,32)
    const int k    = threadIdx.x;
    const int line = k >> 4;
    const int col  = k & 15;
    const f32x4 v  = *reinterpret_cast<const f32x4*>(
        in + (size_t)bb * (D_IN * D_IN) + (size_t)t * D_IN + (k << 2));
    const int c0   = rank36_3(line, 16 + col, 32);

    float* __restrict__ orow = out + ((size_t)bb * D_OUT + o) * D_OUT;
    *reinterpret_cast<f32x4u*>(orow + c0) = v;
}

extern "C" void kernel_launch(void* const* d_in, const int* in_sizes, int n_in,
                              void* d_out, int out_size, void* d_ws, size_t ws_size,
                              hipStream_t stream) {
    const float* in = (const float*)d_in[0];   // (2, 1024, 1024) f32
    float* out = (float*)d_out;                // (2, 7140, 7140) f32

    // zero-fill at rocclr fill speed (graph-capturable memset node)
    hipMemsetAsync(out, 0, (size_t)out_size * sizeof(float), stream);

    hipLaunchKernelGGL(scatter_rows_kernel, dim3(2 * D_IN), dim3(256), 0, stream,
                       in, out);
}

// Round 8
// 76.119 us; speedup vs baseline: 1.1426x; 1.0252x over previous
//
#include <hip/hip_runtime.h>

// out[b] = P @ X[b] @ P^T, P (7140x1024) 0/1 with one 1 per column => scatter:
// out[b][rank(i)][rank(j)] = X[b][i][j], zeros elsewhere.
// hipMemsetAsync zero-fills at rocclr fill speed (~7 TB/s); then a full-row
// writer rewrites each of the 2048 data rows entirely (aligned full-line
// f32x4 stores, 58 MB) — avoiding the partial-line RMW traffic (~116 MB)
// that the 16B unaligned scatter cost in R7.

constexpr int D_IN  = 1024;
constexpr int D_OUT = 7140;            // C(36,3)
constexpr int VROW  = D_OUT / 4;       // 1785 f32x4 per output row

typedef float f32x4 __attribute__((ext_vector_type(4)));

// rank of (a,b,c), 0<=a<b<c<36, among C(36,3) combos (closed form, verified R5-R7)
__device__ __forceinline__ int rank36_3(int a, int b, int c) {
    int s1 = 7140 - (36 - a) * (35 - a) * (34 - a) / 6;
    int s2 = ((34 - a) * (35 - a) - (35 - b) * (36 - b)) / 2;
    return s1 + s2 + (c - b - 1);
}

// one block per data (source) row: write the FULL output row (zeros + data)
__global__ __launch_bounds__(256) void row_writer_kernel(
    const float* __restrict__ in, float* __restrict__ out)
{
    __shared__ __align__(16) short inv[D_OUT];   // output column -> source column, or -1
    __shared__ __align__(16) float srow[D_IN];   // staged source row

    const int bb = blockIdx.x >> 10;             // batch
    const int t  = blockIdx.x & 1023;            // source row index

    for (int q = threadIdx.x; q < D_OUT; q += 256) inv[q] = -1;
    __syncthreads();
    for (int q = threadIdx.x; q < D_IN; q += 256) {
        int ch = q & 3, col = (q >> 2) & 15, line = q >> 6;
        inv[rank36_3(line, 16 + col, 32 + ch)] = (short)q;
    }
    // stage source row (256 lanes x 16B = 4KB, coalesced)
    reinterpret_cast<f32x4*>(srow)[threadIdx.x] =
        reinterpret_cast<const f32x4*>(in + (size_t)bb * (D_IN * D_IN)
                                          + (size_t)t * D_IN)[threadIdx.x];
    __syncthreads();

    const int o = rank36_3(t >> 6, 16 + ((t >> 2) & 15), 32 + (t & 3));
    f32x4* __restrict__ orow =
        reinterpret_cast<f32x4*>(out) + (size_t)((size_t)bb * D_OUT + o) * VROW;

    for (int p = threadIdx.x; p < VROW; p += 256) {
        short4 iv = *reinterpret_cast<const short4*>(&inv[p * 4]);
        f32x4 v;
        v.x = (iv.x >= 0) ? srow[iv.x] : 0.f;
        v.y = (iv.y >= 0) ? srow[iv.y] : 0.f;
        v.z = (iv.z >= 0) ? srow[iv.z] : 0.f;
        v.w = (iv.w >= 0) ? srow[iv.w] : 0.f;
        orow[p] = v;
    }
}

extern "C" void kernel_launch(void* const* d_in, const int* in_sizes, int n_in,
                              void* d_out, int out_size, void* d_ws, size_t ws_size,
                              hipStream_t stream) {
    const float* in = (const float*)d_in[0];   // (2, 1024, 1024) f32
    float* out = (float*)d_out;                // (2, 7140, 7140) f32

    // zero-fill at rocclr fill speed (graph-capturable memset node)
    hipMemsetAsync(out, 0, (size_t)out_size * sizeof(float), stream);

    hipLaunchKernelGGL(row_writer_kernel, dim3(2 * D_IN), dim3(256), 0, stream,
                       in, out);
}